// Round 1
// baseline (2224.903 us; speedup 1.0000x reference)
//
#include <hip/hip_runtime.h>
#include <math.h>

static constexpr int DM = 1024;   // d_model
static constexpr int NH = 16;     // heads
static constexpr int DH = 64;     // head dim

// ---------------------------------------------------------------------------
// GEMM: C[M,N] = A[M,K] @ B[N,K]^T   (row-major fp32, "NT" layout: both
// operands contiguous over K). 64x64 tile, 256 threads, 4x4 per thread.
// LDS pad 17 -> inner-loop reads are broadcast or <=2-way (free).
// ---------------------------------------------------------------------------
__global__ __launch_bounds__(256)
void gemm_nt_64(const float* __restrict__ A, const float* __restrict__ B,
                float* __restrict__ C, int M, int N, int K) {
    __shared__ float As[64][17];
    __shared__ float Bs[64][17];
    const int tid = threadIdx.x;
    const int tx = tid & 15, ty = tid >> 4;
    const size_t m0 = (size_t)blockIdx.y * 64;
    const size_t n0 = (size_t)blockIdx.x * 64;
    float acc[4][4] = {};

    const int rs = tid >> 2;          // 0..63 staging row
    const int gs = (tid & 3) * 4;     // 0,4,8,12 staging col granule
    const float* Ap = A + (m0 + rs) * K;
    const float* Bp = B + (n0 + rs) * K;

    for (int k0 = 0; k0 < K; k0 += 16) {
        float4 av = *(const float4*)(Ap + k0 + gs);
        float4 bv = *(const float4*)(Bp + k0 + gs);
        As[rs][gs + 0] = av.x; As[rs][gs + 1] = av.y;
        As[rs][gs + 2] = av.z; As[rs][gs + 3] = av.w;
        Bs[rs][gs + 0] = bv.x; Bs[rs][gs + 1] = bv.y;
        Bs[rs][gs + 2] = bv.z; Bs[rs][gs + 3] = bv.w;
        __syncthreads();
        #pragma unroll
        for (int kk = 0; kk < 16; ++kk) {
            float a[4], b[4];
            #pragma unroll
            for (int i = 0; i < 4; ++i) a[i] = As[ty * 4 + i][kk];
            #pragma unroll
            for (int j = 0; j < 4; ++j) b[j] = Bs[tx * 4 + j][kk];
            #pragma unroll
            for (int i = 0; i < 4; ++i)
                #pragma unroll
                for (int j = 0; j < 4; ++j)
                    acc[i][j] = fmaf(a[i], b[j], acc[i][j]);
        }
        __syncthreads();
    }
    #pragma unroll
    for (int i = 0; i < 4; ++i) {
        float4 v = make_float4(acc[i][0], acc[i][1], acc[i][2], acc[i][3]);
        *(float4*)&C[(m0 + ty * 4 + i) * N + n0 + tx * 4] = v;
    }
}

// ---------------------------------------------------------------------------
// RoPE (interleaved pairs) applied in-place to Q and K buffers [rows, DM].
// col = h*64 + 2k, angle = pos[s] * theta^(-k/32). Precise sinf/cosf to
// match reference fp32 range reduction (angles up to ~2047 rad).
// ---------------------------------------------------------------------------
__global__ __launch_bounds__(256)
void rope_qk(float* __restrict__ Qb, float* __restrict__ Kb,
             const int* __restrict__ pos, int S, int rows) {
    int idx = blockIdx.x * 256 + threadIdx.x;
    const int per = rows * (DM / 2);
    float* buf = Qb;
    if (idx >= per) { idx -= per; buf = Kb; }
    if (idx >= per) return;
    const int row = idx >> 9;        // / 512 pairs per row
    const int p = idx & 511;
    const int kl = p & 31;           // k within head
    const int h = p >> 5;
    const int col = h * DH + kl * 2;
    const float ang = (float)pos[row % S] * powf(10000.0f, -(float)kl * (1.0f / 32.0f));
    const float c = cosf(ang), s = sinf(ang);
    const size_t base = (size_t)row * DM + col;
    const float x0 = buf[base], x1 = buf[base + 1];
    buf[base]     = c * x0 - s * x1;
    buf[base + 1] = s * x0 + c * x1;
}

// ---------------------------------------------------------------------------
// Flash attention fp32. Block = 256 threads = 4 waves; each wave owns 4
// consecutive q rows (16 rows per block). K/V staged in 64-row LDS tiles.
// Pad 68 floats/row: rows 16B-aligned (float4 reads) and stride==4 mod 32
// gives a bank-even b128 pattern. Online softmax per row; PV via shfl
// broadcast of p (score lives in lane j for k-row j).
// Output written in-place over the Q buffer (each block reads only its own
// Q rows first).
// ---------------------------------------------------------------------------
__global__ __launch_bounds__(256)
void attn_fwd(const float* __restrict__ Q, const float* __restrict__ K,
              const float* __restrict__ V, float* __restrict__ O, int S) {
    __shared__ float Ks[64][68];
    __shared__ float Vs[64][68];
    __shared__ float q_s[16][64];
    const int b = blockIdx.z, h = blockIdx.y;
    const int q0 = blockIdx.x * 16;
    const int tid = threadIdx.x;
    const int lane = tid & 63, w = tid >> 6;
    const size_t rowbase = (size_t)(b * S) * DM + h * DH;

    {   // stage q rows, pre-scaled by 1/sqrt(dh)
        const int r = tid >> 4, g = (tid & 15) * 4;
        float4 qv = *(const float4*)&Q[rowbase + (size_t)(q0 + r) * DM + g];
        const float sc = 0.125f;
        qv.x *= sc; qv.y *= sc; qv.z *= sc; qv.w *= sc;
        *(float4*)&q_s[r][g] = qv;
    }
    __syncthreads();

    float m[4], l[4], acc[4];
    #pragma unroll
    for (int r = 0; r < 4; ++r) { m[r] = -INFINITY; l[r] = 0.f; acc[r] = 0.f; }

    const int nkb = (q0 + 15) / 64 + 1;   // causal: only blocks touching <= q0+15
    for (int kb = 0; kb < nkb; ++kb) {
        #pragma unroll
        for (int it = 0; it < 4; ++it) {  // stage 64x64 K and V (float4/thread)
            const int idx = tid + it * 256;
            const int j = idx >> 4, g = (idx & 15) * 4;
            const size_t gaddr = rowbase + (size_t)(kb * 64 + j) * DM + g;
            *(float4*)&Ks[j][g] = *(const float4*)&K[gaddr];
            *(float4*)&Vs[j][g] = *(const float4*)&V[gaddr];
        }
        __syncthreads();
        #pragma unroll
        for (int r = 0; r < 4; ++r) {
            const int row = q0 + w * 4 + r;
            const int lr = w * 4 + r;
            // lane j computes score(row, kb*64+j)
            float s = 0.f;
            const float4* kr = (const float4*)&Ks[lane][0];
            const float4* qr = (const float4*)&q_s[lr][0];
            #pragma unroll
            for (int d4 = 0; d4 < 16; ++d4) {
                const float4 kv = kr[d4], qv = qr[d4];
                s = fmaf(qv.x, kv.x, s);
                s = fmaf(qv.y, kv.y, s);
                s = fmaf(qv.z, kv.z, s);
                s = fmaf(qv.w, kv.w, s);
            }
            if (kb * 64 + lane > row) s = -INFINITY;
            // online softmax
            float bm = s;
            #pragma unroll
            for (int off = 32; off; off >>= 1)
                bm = fmaxf(bm, __shfl_xor(bm, off));
            const float mn = fmaxf(m[r], bm);
            const float p = __expf(s - mn);
            float ps = p;
            #pragma unroll
            for (int off = 32; off; off >>= 1)
                ps += __shfl_xor(ps, off);
            const float corr = __expf(m[r] - mn);
            l[r] = l[r] * corr + ps;
            acc[r] *= corr;
            m[r] = mn;
            // PV: lane d accumulates out[row][d]
            #pragma unroll
            for (int j = 0; j < 64; ++j) {
                const float pj = __shfl(p, j);
                acc[r] = fmaf(pj, Vs[j][lane], acc[r]);
            }
        }
        __syncthreads();
    }
    #pragma unroll
    for (int r = 0; r < 4; ++r)
        O[rowbase + (size_t)(q0 + w * 4 + r) * DM + lane] = acc[r] / l[r];
}

// ---------------------------------------------------------------------------
extern "C" void kernel_launch(void* const* d_in, const int* in_sizes, int n_in,
                              void* d_out, int out_size, void* d_ws, size_t ws_size,
                              hipStream_t stream) {
    const float* x  = (const float*)d_in[0];
    const int*  pos = (const int*)d_in[1];
    const float* wq = (const float*)d_in[2];
    const float* wk = (const float*)d_in[3];
    const float* wv = (const float*)d_in[4];
    const float* wo = (const float*)d_in[5];
    float* out = (float*)d_out;

    const int S = in_sizes[1];              // 2048
    const int rows = in_sizes[0] / DM;      // B*S = 4096
    const int Bb = rows / S;                // 2

    // ws: Q | K | V (fp32, rows x DM each) = 48 MB. Attention output is
    // written over Q in-place, then projected.
    float* Qb = (float*)d_ws;
    float* Kb = Qb + (size_t)rows * DM;
    float* Vb = Kb + (size_t)rows * DM;

    dim3 gg(DM / 64, rows / 64);
    gemm_nt_64<<<gg, 256, 0, stream>>>(x, wq, Qb, rows, DM, DM);
    gemm_nt_64<<<gg, 256, 0, stream>>>(x, wk, Kb, rows, DM, DM);
    gemm_nt_64<<<gg, 256, 0, stream>>>(x, wv, Vb, rows, DM, DM);

    const int total = 2 * rows * (DM / 2);
    rope_qk<<<(total + 255) / 256, 256, 0, stream>>>(Qb, Kb, pos, S, rows);

    dim3 ga(S / 16, NH, Bb);
    attn_fwd<<<ga, 256, 0, stream>>>(Qb, Kb, Vb, Qb, S);

    gemm_nt_64<<<gg, 256, 0, stream>>>(Qb, wo, out, rows, DM, DM);
}

// Round 2
// 969.725 us; speedup vs baseline: 2.2944x; 2.2944x over previous
//
#include <hip/hip_runtime.h>
#include <hip/hip_bf16.h>
#include <math.h>

static constexpr int DM = 1024;   // d_model
static constexpr int NH = 16;     // heads
static constexpr int DH = 64;     // head dim

typedef __attribute__((ext_vector_type(8))) short short8v;  // 8 bf16 = 4 VGPR
typedef __attribute__((ext_vector_type(4))) float f32x4;

__device__ inline short f2bf(float x) {
    __hip_bfloat16 h = __float2bfloat16(x);
    return *reinterpret_cast<short*>(&h);
}

// ---------------------------------------------------------------------------
// fp32 NT GEMM (unchanged from R1): C[M,N] = A[M,K] @ B[N,K]^T
// ---------------------------------------------------------------------------
__global__ __launch_bounds__(256)
void gemm_nt_64(const float* __restrict__ A, const float* __restrict__ B,
                float* __restrict__ C, int M, int N, int K) {
    __shared__ float As[64][17];
    __shared__ float Bs[64][17];
    const int tid = threadIdx.x;
    const int tx = tid & 15, ty = tid >> 4;
    const size_t m0 = (size_t)blockIdx.y * 64;
    const size_t n0 = (size_t)blockIdx.x * 64;
    float acc[4][4] = {};

    const int rs = tid >> 2;
    const int gs = (tid & 3) * 4;
    const float* Ap = A + (m0 + rs) * K;
    const float* Bp = B + (n0 + rs) * K;

    for (int k0 = 0; k0 < K; k0 += 16) {
        float4 av = *(const float4*)(Ap + k0 + gs);
        float4 bv = *(const float4*)(Bp + k0 + gs);
        As[rs][gs + 0] = av.x; As[rs][gs + 1] = av.y;
        As[rs][gs + 2] = av.z; As[rs][gs + 3] = av.w;
        Bs[rs][gs + 0] = bv.x; Bs[rs][gs + 1] = bv.y;
        Bs[rs][gs + 2] = bv.z; Bs[rs][gs + 3] = bv.w;
        __syncthreads();
        #pragma unroll
        for (int kk = 0; kk < 16; ++kk) {
            float a[4], b[4];
            #pragma unroll
            for (int i = 0; i < 4; ++i) a[i] = As[ty * 4 + i][kk];
            #pragma unroll
            for (int j = 0; j < 4; ++j) b[j] = Bs[tx * 4 + j][kk];
            #pragma unroll
            for (int i = 0; i < 4; ++i)
                #pragma unroll
                for (int j = 0; j < 4; ++j)
                    acc[i][j] = fmaf(a[i], b[j], acc[i][j]);
        }
        __syncthreads();
    }
    #pragma unroll
    for (int i = 0; i < 4; ++i) {
        float4 v = make_float4(acc[i][0], acc[i][1], acc[i][2], acc[i][3]);
        *(float4*)&C[(m0 + ty * 4 + i) * N + n0 + tx * 4] = v;
    }
}

// ---------------------------------------------------------------------------
// RoPE + bf16 convert + per-head reshape.
// Reads Qb/Kb fp32 [B*S][DM]; writes Qh/Kh bf16 [B*H][S][64].
// Q additionally pre-scaled by 1/sqrt(dh)=0.125.
// ---------------------------------------------------------------------------
__global__ __launch_bounds__(256)
void rope_convert(const float* __restrict__ Qb, const float* __restrict__ Kb,
                  const int* __restrict__ pos, short* __restrict__ Qh,
                  short* __restrict__ Kh, int S, int rows) {
    int idx = blockIdx.x * 256 + threadIdx.x;
    const int per = rows * (DM / 2);
    bool isK = false;
    if (idx >= per) { idx -= per; isK = true; }
    if (idx >= per) return;
    const int row = idx >> 9;          // B*S row
    const int rem = idx & 511;
    const int h = rem >> 5, k = rem & 31;
    const float* src = (isK ? Kb : Qb) + (size_t)row * DM + h * DH + 2 * k;
    const float x0 = src[0], x1 = src[1];
    const float ang = (float)pos[row % S] * powf(10000.0f, -(float)k * (1.0f / 32.0f));
    const float c = cosf(ang), sn = sinf(ang);
    float y0 = c * x0 - sn * x1;
    float y1 = sn * x0 + c * x1;
    if (!isK) { y0 *= 0.125f; y1 *= 0.125f; }
    const int b = row / S, sr = row % S;
    short* dst = (isK ? Kh : Qh) + ((size_t)(b * NH + h) * S + sr) * DH + 2 * k;
    const unsigned int pk = ((unsigned int)(unsigned short)f2bf(y1) << 16)
                          | (unsigned short)f2bf(y0);
    *(unsigned int*)dst = pk;   // 4B-aligned (byte offset 4k)
}

// ---------------------------------------------------------------------------
// V: fp32 [B*S][DM] -> bf16 transposed per head Vt[B*H][64][S].
// 64x64 tile via LDS; coalesced float4 in, 32B vector out.
// ---------------------------------------------------------------------------
__global__ __launch_bounds__(256)
void v_transpose(const float* __restrict__ Vb, short* __restrict__ Vt, int S) {
    __shared__ __align__(16) short T[64][72];
    const int bh = blockIdx.y;
    const int b = bh / NH, h = bh % NH;
    const int s0 = blockIdx.x * 64;
    const int tid = threadIdx.x;
    const int r = tid >> 2, g = (tid & 3) * 16;
    #pragma unroll
    for (int it = 0; it < 4; ++it) {
        float4 v = *(const float4*)&Vb[(size_t)(b * S + s0 + r) * DM + h * DH + g + it * 4];
        T[g + it * 4 + 0][r] = f2bf(v.x);
        T[g + it * 4 + 1][r] = f2bf(v.y);
        T[g + it * 4 + 2][r] = f2bf(v.z);
        T[g + it * 4 + 3][r] = f2bf(v.w);
    }
    __syncthreads();
    const int d = tid >> 2, seg = (tid & 3) * 16;
    const uint4* sv = (const uint4*)&T[d][seg];
    uint4* dv = (uint4*)&Vt[((size_t)bh * DH + d) * S + s0 + seg];
    dv[0] = sv[0];
    dv[1] = sv[1];
}

// ---------------------------------------------------------------------------
// MFMA flash attention (bf16 inputs, fp32 accum).
// Block = 256 thr = 4 waves; each wave owns a 16-row q-tile independently
// (no __syncthreads). mfma_f32_16x16x32_bf16:
//   A-frag: lane holds A[l&15][(l>>4)*8 + i]      (assumed; QK and PV both
//   B-frag: lane holds B[(l>>4)*8 + i][l&15]       use identical k-mapping,
//   C/D:    col = l&15, row = (l>>4)*4 + reg       so any k-permutation error
//                                                  cancels — verified layout
//                                                  for C/D per learn_hip m89)
// K/V read directly from global (256KB/head, L2-resident). P round-trips
// through a per-wave LDS buffer (row pad 72 -> even bank-quad spread on
// ds_read_b128).
// ---------------------------------------------------------------------------
__global__ __launch_bounds__(256)
void attn_mfma(const short* __restrict__ Qh, const short* __restrict__ Kh,
               const short* __restrict__ Vt, float* __restrict__ O, int S) {
    __shared__ __align__(16) __hip_bfloat16 P[4][16][72];
    const int b = blockIdx.z, h = blockIdx.y;
    const int bh = b * NH + h;
    const int tid = threadIdx.x;
    const int w = tid >> 6, l = tid & 63;
    const int lo = l & 15, hi = l >> 4;
    const int q0 = (blockIdx.x * 4 + w) * 16;

    const short* Qp = Qh + (size_t)bh * S * DH;
    const short* Kp = Kh + (size_t)bh * S * DH;
    const short* Vp = Vt + (size_t)bh * DH * S;

    // Q A-frags for the two 32-wide d halves
    const short8v qf0 = *(const short8v*)(Qp + (size_t)(q0 + lo) * DH + hi * 8);
    const short8v qf1 = *(const short8v*)(Qp + (size_t)(q0 + lo) * DH + 32 + hi * 8);

    f32x4 o[4];
    float m[4], lsum[4];
    #pragma unroll
    for (int i = 0; i < 4; ++i) {
        o[i] = (f32x4){0.f, 0.f, 0.f, 0.f};
        m[i] = -INFINITY;
        lsum[i] = 0.f;
    }
    const f32x4 z = (f32x4){0.f, 0.f, 0.f, 0.f};

    const int nkb = (q0 + 79) >> 6;   // causal: kv blocks covering k <= q0+15
    for (int kb = 0; kb < nkb; ++kb) {
        const int kvb = kb * 64;
        // ---- QK^T: 4 column tiles of 16 k each, 2 mfma per tile (d halves)
        f32x4 s[4];
        #pragma unroll
        for (int kt = 0; kt < 4; ++kt) {
            const short* kbase = Kp + (size_t)(kvb + kt * 16 + lo) * DH + hi * 8;
            const short8v kf0 = *(const short8v*)(kbase);
            const short8v kf1 = *(const short8v*)(kbase + 32);
            f32x4 acc = z;
            acc = __builtin_amdgcn_mfma_f32_16x16x32_bf16(qf0, kf0, acc, 0, 0, 0);
            acc = __builtin_amdgcn_mfma_f32_16x16x32_bf16(qf1, kf1, acc, 0, 0, 0);
            s[kt] = acc;
        }
        // ---- mask + online softmax (rows live in 16-lane groups)
        float corr[4];
        #pragma unroll
        for (int rg = 0; rg < 4; ++rg) {
            const int q = q0 + hi * 4 + rg;
            float sv[4];
            float bm = -INFINITY;
            #pragma unroll
            for (int kt = 0; kt < 4; ++kt) {
                float v = s[kt][rg];
                if (kvb + kt * 16 + lo > q) v = -INFINITY;
                sv[kt] = v;
                bm = fmaxf(bm, v);
            }
            bm = fmaxf(bm, __shfl_xor(bm, 1));
            bm = fmaxf(bm, __shfl_xor(bm, 2));
            bm = fmaxf(bm, __shfl_xor(bm, 4));
            bm = fmaxf(bm, __shfl_xor(bm, 8));
            const float mn = fmaxf(m[rg], bm);
            float ps = 0.f;
            #pragma unroll
            for (int kt = 0; kt < 4; ++kt) {
                const float p = __expf(sv[kt] - mn);
                ps += p;
                P[w][hi * 4 + rg][kt * 16 + lo] = __float2bfloat16(p);
            }
            ps += __shfl_xor(ps, 1);
            ps += __shfl_xor(ps, 2);
            ps += __shfl_xor(ps, 4);
            ps += __shfl_xor(ps, 8);
            corr[rg] = __expf(m[rg] - mn);
            m[rg] = mn;
            lsum[rg] = lsum[rg] * corr[rg] + ps;
        }
        #pragma unroll
        for (int dt = 0; dt < 4; ++dt)
            #pragma unroll
            for (int rg = 0; rg < 4; ++rg)
                o[dt][rg] *= corr[rg];
        // ---- P (LDS, cross-lane) -> A-frag; V B-frags from global (Vt)
        asm volatile("s_waitcnt lgkmcnt(0)" ::: "memory");
        const short8v pa0 = *(const short8v*)&P[w][lo][hi * 8];
        const short8v pa1 = *(const short8v*)&P[w][lo][32 + hi * 8];
        #pragma unroll
        for (int dt = 0; dt < 4; ++dt) {
            const short* vbase = Vp + (size_t)(dt * 16 + lo) * S + kvb + hi * 8;
            const short8v vb0 = *(const short8v*)(vbase);
            const short8v vb1 = *(const short8v*)(vbase + 32);
            o[dt] = __builtin_amdgcn_mfma_f32_16x16x32_bf16(pa0, vb0, o[dt], 0, 0, 0);
            o[dt] = __builtin_amdgcn_mfma_f32_16x16x32_bf16(pa1, vb1, o[dt], 0, 0, 0);
        }
    }
    // ---- epilogue: O[q][d] = o/lsum, back to row-major [B*S][DM]
    const size_t obase = (size_t)(b * S + q0) * DM + h * DH;
    #pragma unroll
    for (int rg = 0; rg < 4; ++rg) {
        const float inv = 1.0f / lsum[rg];
        #pragma unroll
        for (int dt = 0; dt < 4; ++dt)
            O[obase + (size_t)(hi * 4 + rg) * DM + dt * 16 + lo] = o[dt][rg] * inv;
    }
}

// ---------------------------------------------------------------------------
extern "C" void kernel_launch(void* const* d_in, const int* in_sizes, int n_in,
                              void* d_out, int out_size, void* d_ws, size_t ws_size,
                              hipStream_t stream) {
    const float* x  = (const float*)d_in[0];
    const int*  pos = (const int*)d_in[1];
    const float* wq = (const float*)d_in[2];
    const float* wk = (const float*)d_in[3];
    const float* wv = (const float*)d_in[4];
    const float* wo = (const float*)d_in[5];
    float* out = (float*)d_out;

    const int S = in_sizes[1];              // 2048
    const int rows = in_sizes[0] / DM;      // B*S
    const int Bb = rows / S;

    // ws layout: Qb|Kb|Vb fp32 (16MB each) | Qh|Kh|Vt bf16 (8MB each) = 72MB.
    // Attention output reuses Qb (fp32 Q dead after rope_convert).
    float* Qb = (float*)d_ws;
    float* Kb = Qb + (size_t)rows * DM;
    float* Vb = Kb + (size_t)rows * DM;
    short* Qh = (short*)(Vb + (size_t)rows * DM);
    short* Kh = Qh + (size_t)rows * DM;
    short* Vt = Kh + (size_t)rows * DM;
    float* Ob = Qb;

    dim3 gg(DM / 64, rows / 64);
    gemm_nt_64<<<gg, 256, 0, stream>>>(x, wq, Qb, rows, DM, DM);
    gemm_nt_64<<<gg, 256, 0, stream>>>(x, wk, Kb, rows, DM, DM);
    gemm_nt_64<<<gg, 256, 0, stream>>>(x, wv, Vb, rows, DM, DM);

    const int total = 2 * rows * (DM / 2);
    rope_convert<<<(total + 255) / 256, 256, 0, stream>>>(Qb, Kb, pos, Qh, Kh, S, rows);
    v_transpose<<<dim3(S / 64, Bb * NH), 256, 0, stream>>>(Vb, Vt, S);

    attn_mfma<<<dim3(S / 64, NH, Bb), 256, 0, stream>>>(Qh, Kh, Vt, Ob, S);

    gemm_nt_64<<<gg, 256, 0, stream>>>(Ob, wo, out, rows, DM, DM);
}

// Round 3
// 346.758 us; speedup vs baseline: 6.4163x; 2.7965x over previous
//
#include <hip/hip_runtime.h>
#include <hip/hip_bf16.h>
#include <math.h>

static constexpr int DM = 1024;   // d_model
static constexpr int NH = 16;     // heads
static constexpr int DH = 64;     // head dim
static constexpr int QKV = 3 * DM;

typedef __attribute__((ext_vector_type(8))) short short8v;  // 8 bf16 = 4 VGPR
typedef __attribute__((ext_vector_type(4))) float f32x4;

__device__ inline short f2bf(float x) {
    __hip_bfloat16 h = __float2bfloat16(x);
    return *reinterpret_cast<short*>(&h);
}

// async global->LDS, 16B per lane. LDS dst must be wave-uniform (HW writes
// lane i at dst + i*16); global src is per-lane.
__device__ inline void gload16(const void* g, void* l) {
    __builtin_amdgcn_global_load_lds(
        (const __attribute__((address_space(1))) unsigned int*)g,
        (__attribute__((address_space(3))) unsigned int*)l, 16, 0, 0);
}

// ---------------------------------------------------------------------------
// fp32 -> bf16 convert (vectorized, 4/thread)
// ---------------------------------------------------------------------------
__global__ __launch_bounds__(256)
void f32_to_bf16(const float* __restrict__ src, short* __restrict__ dst, int n) {
    const int i = (blockIdx.x * 256 + threadIdx.x) * 4;
    if (i >= n) return;
    const float4 v = *(const float4*)(src + i);
    short4 o;
    o.x = f2bf(v.x); o.y = f2bf(v.y); o.z = f2bf(v.z); o.w = f2bf(v.w);
    *(short4*)(dst + i) = o;
}

// ---------------------------------------------------------------------------
// bf16 MFMA GEMM, m97 structure: C[M,N] = A[M,K] @ B[N,K]^T.
// 128x128 tile, BK=32, 256 thr = 4 waves (2x2), 4x4 16x16 frags per wave.
// Staging via global_load_lds width=16 into linear row-major [128][32] LDS.
// BF16OUT: 1 -> bf16 C, 0 -> fp32 C.
// ---------------------------------------------------------------------------
template <int BF16OUT>
__global__ __launch_bounds__(256)
void gemm_bt_mfma(const short* __restrict__ A, const short* __restrict__ B,
                  void* __restrict__ Cv, int M, int N, int K) {
    __shared__ __align__(16) short As[128 * 32];
    __shared__ __align__(16) short Bs[128 * 32];
    const int tid = threadIdx.x;
    const int w = tid >> 6, l = tid & 63;
    const int lo = l & 15, hi = l >> 4;
    const int wr = w >> 1, wc = w & 1;
    const size_t m0 = (size_t)blockIdx.y * 128;
    const size_t n0 = (size_t)blockIdx.x * 128;

    // staging: wave w owns chunks 2w,2w+1 (1KB each = 16 rows x 32 cols bf16).
    // lane l -> row_in_chunk l/4, col (l&3)*8.
    const int cr = (w * 2) * 16 + (l >> 2);
    const int cc = (l & 3) * 8;
    const short* Ag0 = A + (m0 + cr) * K + cc;
    const short* Ag1 = Ag0 + (size_t)16 * K;
    const short* Bg0 = B + (n0 + cr) * K + cc;
    const short* Bg1 = Bg0 + (size_t)16 * K;
    short* As0 = As + (w * 2) * 512;   // wave-uniform LDS bases
    short* As1 = As0 + 512;
    short* Bs0 = Bs + (w * 2) * 512;
    short* Bs1 = Bs0 + 512;

    f32x4 acc[4][4];
    #pragma unroll
    for (int mi = 0; mi < 4; ++mi)
        #pragma unroll
        for (int nj = 0; nj < 4; ++nj)
            acc[mi][nj] = (f32x4){0.f, 0.f, 0.f, 0.f};

    const int aoff = (wr * 64 + lo) * 32 + hi * 8;
    const int boff = (wc * 64 + lo) * 32 + hi * 8;

    for (int k0 = 0; k0 < K; k0 += 32) {
        __syncthreads();               // prior ds_reads done before overwrite
        gload16(Ag0 + k0, As0);
        gload16(Ag1 + k0, As1);
        gload16(Bg0 + k0, Bs0);
        gload16(Bg1 + k0, Bs1);
        __syncthreads();               // compiler drains vmcnt before barrier
        short8v af[4], bf[4];
        #pragma unroll
        for (int mi = 0; mi < 4; ++mi)
            af[mi] = *(const short8v*)&As[aoff + mi * 16 * 32];
        #pragma unroll
        for (int nj = 0; nj < 4; ++nj)
            bf[nj] = *(const short8v*)&Bs[boff + nj * 16 * 32];
        #pragma unroll
        for (int mi = 0; mi < 4; ++mi)
            #pragma unroll
            for (int nj = 0; nj < 4; ++nj)
                acc[mi][nj] = __builtin_amdgcn_mfma_f32_16x16x32_bf16(
                    af[mi], bf[nj], acc[mi][nj], 0, 0, 0);
    }

    const size_t mbase = m0 + wr * 64 + hi * 4;
    const size_t nbase = n0 + wc * 64 + lo;
    #pragma unroll
    for (int mi = 0; mi < 4; ++mi)
        #pragma unroll
        for (int nj = 0; nj < 4; ++nj)
            #pragma unroll
            for (int rg = 0; rg < 4; ++rg) {
                const size_t m = mbase + mi * 16 + rg;
                const size_t n = nbase + nj * 16;
                if (BF16OUT)
                    ((short*)Cv)[m * N + n] = f2bf(acc[mi][nj][rg]);
                else
                    ((float*)Cv)[m * N + n] = acc[mi][nj][rg];
            }
}

// ---------------------------------------------------------------------------
// RoPE on bf16 QKV buffer [rows][3072] (Q cols 0.., K cols 1024..).
// fp32 math inside; writes per-head bf16 Qh/Kh [B*H][S][64]; Q scaled 1/8.
// ---------------------------------------------------------------------------
__global__ __launch_bounds__(256)
void rope_bf16(const short* __restrict__ QKVr, const int* __restrict__ pos,
               short* __restrict__ Qh, short* __restrict__ Kh, int S, int rows) {
    int idx = blockIdx.x * 256 + threadIdx.x;
    const int per = rows * (DM / 2);
    bool isK = false;
    if (idx >= per) { idx -= per; isK = true; }
    if (idx >= per) return;
    const int row = idx >> 9;
    const int rem = idx & 511;
    const int h = rem >> 5, k = rem & 31;
    const unsigned pin = *(const unsigned*)(QKVr + (size_t)row * QKV +
                                            (isK ? DM : 0) + h * DH + 2 * k);
    const float x0 = __uint_as_float(pin << 16);
    const float x1 = __uint_as_float(pin & 0xffff0000u);
    const float ang = (float)pos[row % S] * powf(10000.0f, -(float)k * (1.0f / 32.0f));
    const float c = cosf(ang), sn = sinf(ang);
    float y0 = c * x0 - sn * x1;
    float y1 = sn * x0 + c * x1;
    if (!isK) { y0 *= 0.125f; y1 *= 0.125f; }
    const int b = row / S, sr = row % S;
    short* dst = (isK ? Kh : Qh) + ((size_t)(b * NH + h) * S + sr) * DH + 2 * k;
    *(unsigned*)dst = ((unsigned)(unsigned short)f2bf(y1) << 16)
                    | (unsigned short)f2bf(y0);
}

// ---------------------------------------------------------------------------
// V slice of QKV buffer (cols 2048..) -> per-head transposed Vt[B*H][64][S].
// ---------------------------------------------------------------------------
__global__ __launch_bounds__(256)
void v_transpose_bf16(const short* __restrict__ QKVr, short* __restrict__ Vt, int S) {
    __shared__ __align__(16) short T[64][72];
    const int bh = blockIdx.y;
    const int b = bh / NH, h = bh - b * NH;
    const int s0 = blockIdx.x * 64;
    const int tid = threadIdx.x;
    const int r = tid >> 2, seg = (tid & 3) * 16;
    const short* src = QKVr + (size_t)(b * S + s0 + r) * QKV + 2 * DM + h * DH + seg;
    const short8v a0 = *(const short8v*)(src);
    const short8v a1 = *(const short8v*)(src + 8);
    #pragma unroll
    for (int j = 0; j < 8; ++j) T[seg + j][r] = a0[j];
    #pragma unroll
    for (int j = 0; j < 8; ++j) T[seg + 8 + j][r] = a1[j];
    __syncthreads();
    const uint4* sv = (const uint4*)&T[r][seg];
    uint4* dv = (uint4*)&Vt[((size_t)bh * DH + r) * S + s0 + seg];
    dv[0] = sv[0]; dv[1] = sv[1];
}

// ---------------------------------------------------------------------------
// MFMA flash attention (unchanged structure from R2); epilogue now writes
// bf16 row-major Oh[B*S][DM] to feed the output-projection GEMM.
// ---------------------------------------------------------------------------
__global__ __launch_bounds__(256)
void attn_mfma(const short* __restrict__ Qh, const short* __restrict__ Kh,
               const short* __restrict__ Vt, short* __restrict__ Oh, int S) {
    __shared__ __align__(16) __hip_bfloat16 P[4][16][72];
    const int b = blockIdx.z, h = blockIdx.y;
    const int bh = b * NH + h;
    const int tid = threadIdx.x;
    const int w = tid >> 6, l = tid & 63;
    const int lo = l & 15, hi = l >> 4;
    const int q0 = (blockIdx.x * 4 + w) * 16;

    const short* Qp = Qh + (size_t)bh * S * DH;
    const short* Kp = Kh + (size_t)bh * S * DH;
    const short* Vp = Vt + (size_t)bh * DH * S;

    const short8v qf0 = *(const short8v*)(Qp + (size_t)(q0 + lo) * DH + hi * 8);
    const short8v qf1 = *(const short8v*)(Qp + (size_t)(q0 + lo) * DH + 32 + hi * 8);

    f32x4 o[4];
    float m[4], lsum[4];
    #pragma unroll
    for (int i = 0; i < 4; ++i) {
        o[i] = (f32x4){0.f, 0.f, 0.f, 0.f};
        m[i] = -INFINITY;
        lsum[i] = 0.f;
    }
    const f32x4 z = (f32x4){0.f, 0.f, 0.f, 0.f};

    const int nkb = (q0 + 79) >> 6;
    for (int kb = 0; kb < nkb; ++kb) {
        const int kvb = kb * 64;
        f32x4 s[4];
        #pragma unroll
        for (int kt = 0; kt < 4; ++kt) {
            const short* kbase = Kp + (size_t)(kvb + kt * 16 + lo) * DH + hi * 8;
            const short8v kf0 = *(const short8v*)(kbase);
            const short8v kf1 = *(const short8v*)(kbase + 32);
            f32x4 acc = z;
            acc = __builtin_amdgcn_mfma_f32_16x16x32_bf16(qf0, kf0, acc, 0, 0, 0);
            acc = __builtin_amdgcn_mfma_f32_16x16x32_bf16(qf1, kf1, acc, 0, 0, 0);
            s[kt] = acc;
        }
        float corr[4];
        #pragma unroll
        for (int rg = 0; rg < 4; ++rg) {
            const int q = q0 + hi * 4 + rg;
            float sv[4];
            float bm = -INFINITY;
            #pragma unroll
            for (int kt = 0; kt < 4; ++kt) {
                float v = s[kt][rg];
                if (kvb + kt * 16 + lo > q) v = -INFINITY;
                sv[kt] = v;
                bm = fmaxf(bm, v);
            }
            bm = fmaxf(bm, __shfl_xor(bm, 1));
            bm = fmaxf(bm, __shfl_xor(bm, 2));
            bm = fmaxf(bm, __shfl_xor(bm, 4));
            bm = fmaxf(bm, __shfl_xor(bm, 8));
            const float mn = fmaxf(m[rg], bm);
            float ps = 0.f;
            #pragma unroll
            for (int kt = 0; kt < 4; ++kt) {
                const float p = __expf(sv[kt] - mn);
                ps += p;
                P[w][hi * 4 + rg][kt * 16 + lo] = __float2bfloat16(p);
            }
            ps += __shfl_xor(ps, 1);
            ps += __shfl_xor(ps, 2);
            ps += __shfl_xor(ps, 4);
            ps += __shfl_xor(ps, 8);
            corr[rg] = __expf(m[rg] - mn);
            m[rg] = mn;
            lsum[rg] = lsum[rg] * corr[rg] + ps;
        }
        #pragma unroll
        for (int dt = 0; dt < 4; ++dt)
            #pragma unroll
            for (int rg = 0; rg < 4; ++rg)
                o[dt][rg] *= corr[rg];
        asm volatile("s_waitcnt lgkmcnt(0)" ::: "memory");
        const short8v pa0 = *(const short8v*)&P[w][lo][hi * 8];
        const short8v pa1 = *(const short8v*)&P[w][lo][32 + hi * 8];
        #pragma unroll
        for (int dt = 0; dt < 4; ++dt) {
            const short* vbase = Vp + (size_t)(dt * 16 + lo) * S + kvb + hi * 8;
            const short8v vb0 = *(const short8v*)(vbase);
            const short8v vb1 = *(const short8v*)(vbase + 32);
            o[dt] = __builtin_amdgcn_mfma_f32_16x16x32_bf16(pa0, vb0, o[dt], 0, 0, 0);
            o[dt] = __builtin_amdgcn_mfma_f32_16x16x32_bf16(pa1, vb1, o[dt], 0, 0, 0);
        }
    }
    short* Op = Oh + (size_t)(b * S + q0) * DM + h * DH;
    #pragma unroll
    for (int rg = 0; rg < 4; ++rg) {
        const float inv = 1.0f / lsum[rg];
        #pragma unroll
        for (int dt = 0; dt < 4; ++dt)
            Op[(size_t)(hi * 4 + rg) * DM + dt * 16 + lo] = f2bf(o[dt][rg] * inv);
    }
}

// ---------------------------------------------------------------------------
extern "C" void kernel_launch(void* const* d_in, const int* in_sizes, int n_in,
                              void* d_out, int out_size, void* d_ws, size_t ws_size,
                              hipStream_t stream) {
    const float* x  = (const float*)d_in[0];
    const int*  pos = (const int*)d_in[1];
    const float* wq = (const float*)d_in[2];
    const float* wk = (const float*)d_in[3];
    const float* wv = (const float*)d_in[4];
    const float* wo = (const float*)d_in[5];
    float* out = (float*)d_out;

    const int S = in_sizes[1];              // 2048
    const int rows = in_sizes[0] / DM;      // B*S
    const int Bb = rows / S;

    // ws (shorts): xh 4M | wqkv 3M | woh 1M | QKVr 12M | Qh 4M | Kh 4M |
    // Vt 4M | Oh 4M  = 36M shorts = 72 MB (same footprint as R2).
    short* xh   = (short*)d_ws;
    short* wqkv = xh + (size_t)rows * DM;
    short* woh  = wqkv + (size_t)QKV * DM;
    short* QKVr = woh + (size_t)DM * DM;
    short* Qh   = QKVr + (size_t)rows * QKV;
    short* Kh   = Qh + (size_t)rows * DM;
    short* Vt   = Kh + (size_t)rows * DM;
    short* Oh   = Vt + (size_t)rows * DM;

    const int nx = rows * DM;
    const int nw = DM * DM;
    f32_to_bf16<<<(nx / 4 + 255) / 256, 256, 0, stream>>>(x, xh, nx);
    f32_to_bf16<<<(nw / 4 + 255) / 256, 256, 0, stream>>>(wq, wqkv, nw);
    f32_to_bf16<<<(nw / 4 + 255) / 256, 256, 0, stream>>>(wk, wqkv + nw, nw);
    f32_to_bf16<<<(nw / 4 + 255) / 256, 256, 0, stream>>>(wv, wqkv + 2 * nw, nw);
    f32_to_bf16<<<(nw / 4 + 255) / 256, 256, 0, stream>>>(wo, woh, nw);

    gemm_bt_mfma<1><<<dim3(QKV / 128, rows / 128), 256, 0, stream>>>(
        xh, wqkv, QKVr, rows, QKV, DM);

    const int total = 2 * rows * (DM / 2);
    rope_bf16<<<(total + 255) / 256, 256, 0, stream>>>(QKVr, pos, Qh, Kh, S, rows);
    v_transpose_bf16<<<dim3(S / 64, Bb * NH), 256, 0, stream>>>(QKVr, Vt, S);

    attn_mfma<<<dim3(S / 64, NH, Bb), 256, 0, stream>>>(Qh, Kh, Vt, Oh, S);

    gemm_bt_mfma<0><<<dim3(DM / 128, rows / 128), 256, 0, stream>>>(
        Oh, woh, out, rows, DM, DM);
}

// Round 5
// 252.915 us; speedup vs baseline: 8.7971x; 1.3710x over previous
//
#include <hip/hip_runtime.h>
#include <hip/hip_bf16.h>
#include <math.h>

static constexpr int DM = 1024;   // d_model
static constexpr int NH = 16;     // heads
static constexpr int DH = 64;     // head dim
static constexpr int QKV = 3 * DM;

typedef __attribute__((ext_vector_type(8))) short short8v;  // 8 bf16 = 4 VGPR
typedef __attribute__((ext_vector_type(4))) float f32x4;

__device__ inline short f2bf(float x) {
    __hip_bfloat16 h = __float2bfloat16(x);
    return *reinterpret_cast<short*>(&h);
}

// async global->LDS, 16B per lane. LDS dst must be wave-uniform (HW writes
// lane i at dst + i*16); global src is per-lane.
__device__ inline void gload16(const void* g, void* l) {
    __builtin_amdgcn_global_load_lds(
        (const __attribute__((address_space(1))) unsigned int*)g,
        (__attribute__((address_space(3))) unsigned int*)l, 16, 0, 0);
}

// ---------------------------------------------------------------------------
// fp32 -> bf16 convert (vectorized, 4/thread)
// ---------------------------------------------------------------------------
__global__ __launch_bounds__(256)
void f32_to_bf16(const float* __restrict__ src, short* __restrict__ dst, int n) {
    const int i = (blockIdx.x * 256 + threadIdx.x) * 4;
    if (i >= n) return;
    const float4 v = *(const float4*)(src + i);
    short4 o;
    o.x = f2bf(v.x); o.y = f2bf(v.y); o.z = f2bf(v.z); o.w = f2bf(v.w);
    *(short4*)(dst + i) = o;
}

// ---------------------------------------------------------------------------
// bf16 MFMA GEMM, m97 structure (unchanged from R3, passing).
// ---------------------------------------------------------------------------
template <int BF16OUT>
__global__ __launch_bounds__(256)
void gemm_bt_mfma(const short* __restrict__ A, const short* __restrict__ B,
                  void* __restrict__ Cv, int M, int N, int K) {
    __shared__ __align__(16) short As[128 * 32];
    __shared__ __align__(16) short Bs[128 * 32];
    const int tid = threadIdx.x;
    const int w = tid >> 6, l = tid & 63;
    const int lo = l & 15, hi = l >> 4;
    const int wr = w >> 1, wc = w & 1;
    const size_t m0 = (size_t)blockIdx.y * 128;
    const size_t n0 = (size_t)blockIdx.x * 128;

    const int cr = (w * 2) * 16 + (l >> 2);
    const int cc = (l & 3) * 8;
    const short* Ag0 = A + (m0 + cr) * K + cc;
    const short* Ag1 = Ag0 + (size_t)16 * K;
    const short* Bg0 = B + (n0 + cr) * K + cc;
    const short* Bg1 = Bg0 + (size_t)16 * K;
    short* As0 = As + (w * 2) * 512;
    short* As1 = As0 + 512;
    short* Bs0 = Bs + (w * 2) * 512;
    short* Bs1 = Bs0 + 512;

    f32x4 acc[4][4];
    #pragma unroll
    for (int mi = 0; mi < 4; ++mi)
        #pragma unroll
        for (int nj = 0; nj < 4; ++nj)
            acc[mi][nj] = (f32x4){0.f, 0.f, 0.f, 0.f};

    const int aoff = (wr * 64 + lo) * 32 + hi * 8;
    const int boff = (wc * 64 + lo) * 32 + hi * 8;

    for (int k0 = 0; k0 < K; k0 += 32) {
        __syncthreads();
        gload16(Ag0 + k0, As0);
        gload16(Ag1 + k0, As1);
        gload16(Bg0 + k0, Bs0);
        gload16(Bg1 + k0, Bs1);
        __syncthreads();
        short8v af[4], bf[4];
        #pragma unroll
        for (int mi = 0; mi < 4; ++mi)
            af[mi] = *(const short8v*)&As[aoff + mi * 16 * 32];
        #pragma unroll
        for (int nj = 0; nj < 4; ++nj)
            bf[nj] = *(const short8v*)&Bs[boff + nj * 16 * 32];
        #pragma unroll
        for (int mi = 0; mi < 4; ++mi)
            #pragma unroll
            for (int nj = 0; nj < 4; ++nj)
                acc[mi][nj] = __builtin_amdgcn_mfma_f32_16x16x32_bf16(
                    af[mi], bf[nj], acc[mi][nj], 0, 0, 0);
    }

    const size_t mbase = m0 + wr * 64 + hi * 4;
    const size_t nbase = n0 + wc * 64 + lo;
    #pragma unroll
    for (int mi = 0; mi < 4; ++mi)
        #pragma unroll
        for (int nj = 0; nj < 4; ++nj)
            #pragma unroll
            for (int rg = 0; rg < 4; ++rg) {
                const size_t m = mbase + mi * 16 + rg;
                const size_t n = nbase + nj * 16;
                if (BF16OUT)
                    ((short*)Cv)[m * N + n] = f2bf(acc[mi][nj][rg]);
                else
                    ((float*)Cv)[m * N + n] = acc[mi][nj][rg];
            }
}

// ---------------------------------------------------------------------------
// RoPE on bf16 QKV buffer (R3 numerics: Q scaled by 1/8 only).
// ---------------------------------------------------------------------------
__global__ __launch_bounds__(256)
void rope_bf16(const short* __restrict__ QKVr, const int* __restrict__ pos,
               short* __restrict__ Qh, short* __restrict__ Kh, int S, int rows) {
    int idx = blockIdx.x * 256 + threadIdx.x;
    const int per = rows * (DM / 2);
    bool isK = false;
    if (idx >= per) { idx -= per; isK = true; }
    if (idx >= per) return;
    const int row = idx >> 9;
    const int rem = idx & 511;
    const int h = rem >> 5, k = rem & 31;
    const unsigned pin = *(const unsigned*)(QKVr + (size_t)row * QKV +
                                            (isK ? DM : 0) + h * DH + 2 * k);
    const float x0 = __uint_as_float(pin << 16);
    const float x1 = __uint_as_float(pin & 0xffff0000u);
    const float ang = (float)pos[row % S] * powf(10000.0f, -(float)k * (1.0f / 32.0f));
    const float c = cosf(ang), sn = sinf(ang);
    float y0 = c * x0 - sn * x1;
    float y1 = sn * x0 + c * x1;
    if (!isK) { y0 *= 0.125f; y1 *= 0.125f; }
    const int b = row / S, sr = row % S;
    short* dst = (isK ? Kh : Qh) + ((size_t)(b * NH + h) * S + sr) * DH + 2 * k;
    *(unsigned*)dst = ((unsigned)(unsigned short)f2bf(y1) << 16)
                    | (unsigned short)f2bf(y0);
}

// ---------------------------------------------------------------------------
// V slice of QKV buffer -> per-head transposed Vt[B*H][64][S]. (unchanged)
// ---------------------------------------------------------------------------
__global__ __launch_bounds__(256)
void v_transpose_bf16(const short* __restrict__ QKVr, short* __restrict__ Vt, int S) {
    __shared__ __align__(16) short T[64][72];
    const int bh = blockIdx.y;
    const int b = bh / NH, h = bh - b * NH;
    const int s0 = blockIdx.x * 64;
    const int tid = threadIdx.x;
    const int r = tid >> 2, seg = (tid & 3) * 16;
    const short* src = QKVr + (size_t)(b * S + s0 + r) * QKV + 2 * DM + h * DH + seg;
    const short8v a0 = *(const short8v*)(src);
    const short8v a1 = *(const short8v*)(src + 8);
    #pragma unroll
    for (int j = 0; j < 8; ++j) T[seg + j][r] = a0[j];
    #pragma unroll
    for (int j = 0; j < 8; ++j) T[seg + 8 + j][r] = a1[j];
    __syncthreads();
    const uint4* sv = (const uint4*)&T[r][seg];
    uint4* dv = (uint4*)&Vt[((size_t)bh * DH + r) * S + s0 + seg];
    dv[0] = sv[0]; dv[1] = sv[1];
}

// ---------------------------------------------------------------------------
// MFMA flash attention, R5 = R3 dataflow + causal pairing (sequential).
// Wave w of block x handles q-tiles p = x*4+w and T-1-p, one after the
// other. Every wave does exactly nkb(p) + nkb(T-1-p) = 33 kv-iterations
// -> perfectly flat load, no tail. No __syncthreads (waves independent);
// K/V fragments read directly from global (L2-resident); P round-trips
// through a per-wave LDS buffer (identical to the R3 passing kernel).
// ---------------------------------------------------------------------------
__global__ __launch_bounds__(256)
void attn_mfma(const short* __restrict__ Qh, const short* __restrict__ Kh,
               const short* __restrict__ Vt, short* __restrict__ Oh, int S) {
    __shared__ __align__(16) __hip_bfloat16 P[4][16][72];
    const int b = blockIdx.z, h = blockIdx.y;
    const int bh = b * NH + h;
    const int tid = threadIdx.x;
    const int w = tid >> 6, l = tid & 63;
    const int lo = l & 15, hi = l >> 4;
    const int T = S >> 4;
    const int p = blockIdx.x * 4 + w;

    const short* Qp = Qh + (size_t)bh * S * DH;
    const short* Kp = Kh + (size_t)bh * S * DH;
    const short* Vp = Vt + (size_t)bh * DH * S;

    for (int t = 0; t < 2; ++t) {
        const int q0 = (t == 0 ? p : T - 1 - p) << 4;

        const short8v qf0 = *(const short8v*)(Qp + (size_t)(q0 + lo) * DH + hi * 8);
        const short8v qf1 = *(const short8v*)(Qp + (size_t)(q0 + lo) * DH + 32 + hi * 8);

        f32x4 o[4];
        float m[4], lsum[4];
        #pragma unroll
        for (int i = 0; i < 4; ++i) {
            o[i] = (f32x4){0.f, 0.f, 0.f, 0.f};
            m[i] = -INFINITY;
            lsum[i] = 0.f;
        }
        const f32x4 z = (f32x4){0.f, 0.f, 0.f, 0.f};

        const int nkb = (q0 + 79) >> 6;
        for (int kb = 0; kb < nkb; ++kb) {
            const int kvb = kb * 64;
            f32x4 s[4];
            #pragma unroll
            for (int kt = 0; kt < 4; ++kt) {
                const short* kbase = Kp + (size_t)(kvb + kt * 16 + lo) * DH + hi * 8;
                const short8v kf0 = *(const short8v*)(kbase);
                const short8v kf1 = *(const short8v*)(kbase + 32);
                f32x4 acc = z;
                acc = __builtin_amdgcn_mfma_f32_16x16x32_bf16(qf0, kf0, acc, 0, 0, 0);
                acc = __builtin_amdgcn_mfma_f32_16x16x32_bf16(qf1, kf1, acc, 0, 0, 0);
                s[kt] = acc;
            }
            float corr[4];
            #pragma unroll
            for (int rg = 0; rg < 4; ++rg) {
                const int q = q0 + hi * 4 + rg;
                float sv[4];
                float bm = -INFINITY;
                #pragma unroll
                for (int kt = 0; kt < 4; ++kt) {
                    float v = s[kt][rg];
                    if (kvb + kt * 16 + lo > q) v = -INFINITY;
                    sv[kt] = v;
                    bm = fmaxf(bm, v);
                }
                bm = fmaxf(bm, __shfl_xor(bm, 1));
                bm = fmaxf(bm, __shfl_xor(bm, 2));
                bm = fmaxf(bm, __shfl_xor(bm, 4));
                bm = fmaxf(bm, __shfl_xor(bm, 8));
                const float mn = fmaxf(m[rg], bm);
                float ps = 0.f;
                #pragma unroll
                for (int kt = 0; kt < 4; ++kt) {
                    const float pv = __expf(sv[kt] - mn);
                    ps += pv;
                    P[w][hi * 4 + rg][kt * 16 + lo] = __float2bfloat16(pv);
                }
                ps += __shfl_xor(ps, 1);
                ps += __shfl_xor(ps, 2);
                ps += __shfl_xor(ps, 4);
                ps += __shfl_xor(ps, 8);
                corr[rg] = __expf(m[rg] - mn);
                m[rg] = mn;
                lsum[rg] = lsum[rg] * corr[rg] + ps;
            }
            #pragma unroll
            for (int dt = 0; dt < 4; ++dt)
                #pragma unroll
                for (int rg = 0; rg < 4; ++rg)
                    o[dt][rg] *= corr[rg];
            asm volatile("s_waitcnt lgkmcnt(0)" ::: "memory");
            const short8v pa0 = *(const short8v*)&P[w][lo][hi * 8];
            const short8v pa1 = *(const short8v*)&P[w][lo][32 + hi * 8];
            #pragma unroll
            for (int dt = 0; dt < 4; ++dt) {
                const short* vbase = Vp + (size_t)(dt * 16 + lo) * S + kvb + hi * 8;
                const short8v vb0 = *(const short8v*)(vbase);
                const short8v vb1 = *(const short8v*)(vbase + 32);
                o[dt] = __builtin_amdgcn_mfma_f32_16x16x32_bf16(pa0, vb0, o[dt], 0, 0, 0);
                o[dt] = __builtin_amdgcn_mfma_f32_16x16x32_bf16(pa1, vb1, o[dt], 0, 0, 0);
            }
        }
        short* Op = Oh + (size_t)(b * S + q0) * DM + h * DH;
        #pragma unroll
        for (int rg = 0; rg < 4; ++rg) {
            const float inv = 1.0f / lsum[rg];
            #pragma unroll
            for (int dt = 0; dt < 4; ++dt)
                Op[(size_t)(hi * 4 + rg) * DM + dt * 16 + lo] = f2bf(o[dt][rg] * inv);
        }
    }
}

// ---------------------------------------------------------------------------
extern "C" void kernel_launch(void* const* d_in, const int* in_sizes, int n_in,
                              void* d_out, int out_size, void* d_ws, size_t ws_size,
                              hipStream_t stream) {
    const float* x  = (const float*)d_in[0];
    const int*  pos = (const int*)d_in[1];
    const float* wq = (const float*)d_in[2];
    const float* wk = (const float*)d_in[3];
    const float* wv = (const float*)d_in[4];
    const float* wo = (const float*)d_in[5];
    float* out = (float*)d_out;

    const int S = in_sizes[1];              // 2048
    const int rows = in_sizes[0] / DM;      // B*S
    const int Bb = rows / S;

    short* xh   = (short*)d_ws;
    short* wqkv = xh + (size_t)rows * DM;
    short* woh  = wqkv + (size_t)QKV * DM;
    short* QKVr = woh + (size_t)DM * DM;
    short* Qh   = QKVr + (size_t)rows * QKV;
    short* Kh   = Qh + (size_t)rows * DM;
    short* Vt   = Kh + (size_t)rows * DM;
    short* Oh   = Vt + (size_t)rows * DM;

    const int nx = rows * DM;
    const int nw = DM * DM;
    f32_to_bf16<<<(nx / 4 + 255) / 256, 256, 0, stream>>>(x, xh, nx);
    f32_to_bf16<<<(nw / 4 + 255) / 256, 256, 0, stream>>>(wq, wqkv, nw);
    f32_to_bf16<<<(nw / 4 + 255) / 256, 256, 0, stream>>>(wk, wqkv + nw, nw);
    f32_to_bf16<<<(nw / 4 + 255) / 256, 256, 0, stream>>>(wv, wqkv + 2 * nw, nw);
    f32_to_bf16<<<(nw / 4 + 255) / 256, 256, 0, stream>>>(wo, woh, nw);

    gemm_bt_mfma<1><<<dim3(QKV / 128, rows / 128), 256, 0, stream>>>(
        xh, wqkv, QKVr, rows, QKV, DM);

    const int total = 2 * rows * (DM / 2);
    rope_bf16<<<(total + 255) / 256, 256, 0, stream>>>(QKVr, pos, Qh, Kh, S, rows);
    v_transpose_bf16<<<dim3(S / 64, Bb * NH), 256, 0, stream>>>(QKVr, Vt, S);

    attn_mfma<<<dim3(S / 128, NH, Bb), 256, 0, stream>>>(Qh, Kh, Vt, Oh, S);

    gemm_bt_mfma<0><<<dim3(DM / 128, rows / 128), 256, 0, stream>>>(
        Oh, woh, out, rows, DM, DM);
}

// Round 6
// 223.221 us; speedup vs baseline: 9.9673x; 1.1330x over previous
//
#include <hip/hip_runtime.h>
#include <hip/hip_bf16.h>
#include <math.h>

static constexpr int DM = 1024;   // d_model
static constexpr int NH = 16;     // heads
static constexpr int DH = 64;     // head dim
static constexpr int QKV = 3 * DM;

typedef __attribute__((ext_vector_type(8))) short short8v;  // 8 bf16 = 4 VGPR
typedef __attribute__((ext_vector_type(4))) float f32x4;

__device__ inline short f2bf(float x) {
    __hip_bfloat16 h = __float2bfloat16(x);
    return *reinterpret_cast<short*>(&h);
}

// async global->LDS, 16B per lane. LDS dst must be wave-uniform (HW writes
// lane i at dst + i*16); global src is per-lane.
__device__ inline void gload16(const void* g, void* l) {
    __builtin_amdgcn_global_load_lds(
        (const __attribute__((address_space(1))) unsigned int*)g,
        (__attribute__((address_space(3))) unsigned int*)l, 16, 0, 0);
}

// ---------------------------------------------------------------------------
// Fused fp32 -> bf16 convert for all five inputs (one launch).
// Boundaries are multiples of 4 elements, so float4 chunks never straddle.
// ---------------------------------------------------------------------------
__global__ __launch_bounds__(256)
void convert_inputs(const float* __restrict__ x,  const float* __restrict__ wq,
                    const float* __restrict__ wk, const float* __restrict__ wv,
                    const float* __restrict__ wo, short* __restrict__ xh,
                    short* __restrict__ wqkv, short* __restrict__ woh,
                    int nx, int nw) {
    const int i = (blockIdx.x * 256 + threadIdx.x) * 4;
    const float* src;
    short* dst;
    int off;
    if (i < nx)                { src = x;  dst = xh;            off = i; }
    else if (i < nx + nw)      { src = wq; dst = wqkv;          off = i - nx; }
    else if (i < nx + 2 * nw)  { src = wk; dst = wqkv + nw;     off = i - nx - nw; }
    else if (i < nx + 3 * nw)  { src = wv; dst = wqkv + 2 * nw; off = i - nx - 2 * nw; }
    else if (i < nx + 4 * nw)  { src = wo; dst = woh;           off = i - nx - 3 * nw; }
    else return;
    const float4 v = *(const float4*)(src + off);
    short4 o;
    o.x = f2bf(v.x); o.y = f2bf(v.y); o.z = f2bf(v.z); o.w = f2bf(v.w);
    *(short4*)(dst + off) = o;
}

// ---------------------------------------------------------------------------
// bf16 MFMA GEMM, m97 structure (unchanged, passing).
// ---------------------------------------------------------------------------
template <int BF16OUT>
__global__ __launch_bounds__(256)
void gemm_bt_mfma(const short* __restrict__ A, const short* __restrict__ B,
                  void* __restrict__ Cv, int M, int N, int K) {
    __shared__ __align__(16) short As[128 * 32];
    __shared__ __align__(16) short Bs[128 * 32];
    const int tid = threadIdx.x;
    const int w = tid >> 6, l = tid & 63;
    const int lo = l & 15, hi = l >> 4;
    const int wr = w >> 1, wc = w & 1;
    const size_t m0 = (size_t)blockIdx.y * 128;
    const size_t n0 = (size_t)blockIdx.x * 128;

    const int cr = (w * 2) * 16 + (l >> 2);
    const int cc = (l & 3) * 8;
    const short* Ag0 = A + (m0 + cr) * K + cc;
    const short* Ag1 = Ag0 + (size_t)16 * K;
    const short* Bg0 = B + (n0 + cr) * K + cc;
    const short* Bg1 = Bg0 + (size_t)16 * K;
    short* As0 = As + (w * 2) * 512;
    short* As1 = As0 + 512;
    short* Bs0 = Bs + (w * 2) * 512;
    short* Bs1 = Bs0 + 512;

    f32x4 acc[4][4];
    #pragma unroll
    for (int mi = 0; mi < 4; ++mi)
        #pragma unroll
        for (int nj = 0; nj < 4; ++nj)
            acc[mi][nj] = (f32x4){0.f, 0.f, 0.f, 0.f};

    const int aoff = (wr * 64 + lo) * 32 + hi * 8;
    const int boff = (wc * 64 + lo) * 32 + hi * 8;

    for (int k0 = 0; k0 < K; k0 += 32) {
        __syncthreads();
        gload16(Ag0 + k0, As0);
        gload16(Ag1 + k0, As1);
        gload16(Bg0 + k0, Bs0);
        gload16(Bg1 + k0, Bs1);
        __syncthreads();
        short8v af[4], bf[4];
        #pragma unroll
        for (int mi = 0; mi < 4; ++mi)
            af[mi] = *(const short8v*)&As[aoff + mi * 16 * 32];
        #pragma unroll
        for (int nj = 0; nj < 4; ++nj)
            bf[nj] = *(const short8v*)&Bs[boff + nj * 16 * 32];
        #pragma unroll
        for (int mi = 0; mi < 4; ++mi)
            #pragma unroll
            for (int nj = 0; nj < 4; ++nj)
                acc[mi][nj] = __builtin_amdgcn_mfma_f32_16x16x32_bf16(
                    af[mi], bf[nj], acc[mi][nj], 0, 0, 0);
    }

    const size_t mbase = m0 + wr * 64 + hi * 4;
    const size_t nbase = n0 + wc * 64 + lo;
    #pragma unroll
    for (int mi = 0; mi < 4; ++mi)
        #pragma unroll
        for (int nj = 0; nj < 4; ++nj)
            #pragma unroll
            for (int rg = 0; rg < 4; ++rg) {
                const size_t m = mbase + mi * 16 + rg;
                const size_t n = nbase + nj * 16;
                if (BF16OUT)
                    ((short*)Cv)[m * N + n] = f2bf(acc[mi][nj][rg]);
                else
                    ((float*)Cv)[m * N + n] = acc[mi][nj][rg];
            }
}

// ---------------------------------------------------------------------------
// RoPE on bf16 QKV buffer (Q scaled by 1/8). (unchanged, passing)
// ---------------------------------------------------------------------------
__global__ __launch_bounds__(256)
void rope_bf16(const short* __restrict__ QKVr, const int* __restrict__ pos,
               short* __restrict__ Qh, short* __restrict__ Kh, int S, int rows) {
    int idx = blockIdx.x * 256 + threadIdx.x;
    const int per = rows * (DM / 2);
    bool isK = false;
    if (idx >= per) { idx -= per; isK = true; }
    if (idx >= per) return;
    const int row = idx >> 9;
    const int rem = idx & 511;
    const int h = rem >> 5, k = rem & 31;
    const unsigned pin = *(const unsigned*)(QKVr + (size_t)row * QKV +
                                            (isK ? DM : 0) + h * DH + 2 * k);
    const float x0 = __uint_as_float(pin << 16);
    const float x1 = __uint_as_float(pin & 0xffff0000u);
    const float ang = (float)pos[row % S] * powf(10000.0f, -(float)k * (1.0f / 32.0f));
    const float c = cosf(ang), sn = sinf(ang);
    float y0 = c * x0 - sn * x1;
    float y1 = sn * x0 + c * x1;
    if (!isK) { y0 *= 0.125f; y1 *= 0.125f; }
    const int b = row / S, sr = row % S;
    short* dst = (isK ? Kh : Qh) + ((size_t)(b * NH + h) * S + sr) * DH + 2 * k;
    *(unsigned*)dst = ((unsigned)(unsigned short)f2bf(y1) << 16)
                    | (unsigned short)f2bf(y0);
}

// ---------------------------------------------------------------------------
// V slice of QKV buffer -> per-head transposed Vt[B*H][64][S]. (unchanged)
// ---------------------------------------------------------------------------
__global__ __launch_bounds__(256)
void v_transpose_bf16(const short* __restrict__ QKVr, short* __restrict__ Vt, int S) {
    __shared__ __align__(16) short T[64][72];
    const int bh = blockIdx.y;
    const int b = bh / NH, h = bh - b * NH;
    const int s0 = blockIdx.x * 64;
    const int tid = threadIdx.x;
    const int r = tid >> 2, seg = (tid & 3) * 16;
    const short* src = QKVr + (size_t)(b * S + s0 + r) * QKV + 2 * DM + h * DH + seg;
    const short8v a0 = *(const short8v*)(src);
    const short8v a1 = *(const short8v*)(src + 8);
    #pragma unroll
    for (int j = 0; j < 8; ++j) T[seg + j][r] = a0[j];
    #pragma unroll
    for (int j = 0; j < 8; ++j) T[seg + 8 + j][r] = a1[j];
    __syncthreads();
    const uint4* sv = (const uint4*)&T[r][seg];
    uint4* dv = (uint4*)&Vt[((size_t)bh * DH + r) * S + s0 + seg];
    dv[0] = sv[0]; dv[1] = sv[1];
}

// ---------------------------------------------------------------------------
// MFMA flash attention, R6 = R5 + interleaved pair processing.
// Wave w handles q-tiles B=(T-1-p) and F=p INSIDE one kb loop:
//  - K and V fragments loaded ONCE from global, shared by both tiles
//    (half the load traffic of R5's sequential version);
//  - V fragments issued BEFORE the softmax chain (latency hides under it);
//  - two independent softmax chains give ILP where TLP is grid-capped.
// Dataflow otherwise identical to the passing R3/R5 kernel: global K/V
// fragment reads, per-wave LDS P round-trip, __expf, no __syncthreads.
// ---------------------------------------------------------------------------
__global__ __launch_bounds__(256)
void attn_mfma(const short* __restrict__ Qh, const short* __restrict__ Kh,
               const short* __restrict__ Vt, short* __restrict__ Oh, int S) {
    __shared__ __align__(16) __hip_bfloat16 P[4][2][16][72];
    const int b = blockIdx.z, h = blockIdx.y;
    const int bh = b * NH + h;
    const int tid = threadIdx.x;
    const int w = tid >> 6, l = tid & 63;
    const int lo = l & 15, hi = l >> 4;
    const int T = S >> 4;
    const int p = blockIdx.x * 4 + w;
    const int q0B = (T - 1 - p) << 4;
    const int q0F = p << 4;
    const int nkbB = (q0B + 79) >> 6;
    const int nkbF = (q0F + 79) >> 6;

    const short* Qp = Qh + (size_t)bh * S * DH;
    const short* Kp = Kh + (size_t)bh * S * DH;
    const short* Vp = Vt + (size_t)bh * DH * S;

    const short8v qB0 = *(const short8v*)(Qp + (size_t)(q0B + lo) * DH + hi * 8);
    const short8v qB1 = *(const short8v*)(Qp + (size_t)(q0B + lo) * DH + 32 + hi * 8);
    const short8v qF0 = *(const short8v*)(Qp + (size_t)(q0F + lo) * DH + hi * 8);
    const short8v qF1 = *(const short8v*)(Qp + (size_t)(q0F + lo) * DH + 32 + hi * 8);

    f32x4 oB[4], oF[4];
    float mB[4], lB[4], mF[4], lF[4];
    #pragma unroll
    for (int i = 0; i < 4; ++i) {
        oB[i] = (f32x4){0.f, 0.f, 0.f, 0.f};
        oF[i] = (f32x4){0.f, 0.f, 0.f, 0.f};
        mB[i] = -INFINITY; lB[i] = 0.f;
        mF[i] = -INFINITY; lF[i] = 0.f;
    }
    const f32x4 z = (f32x4){0.f, 0.f, 0.f, 0.f};

    for (int kb = 0; kb < nkbB; ++kb) {
        const int kvb = kb * 64;
        const bool actF = kb < nkbF;

        // ---- K fragments (shared by both tiles)
        short8v kf0[4], kf1[4];
        #pragma unroll
        for (int kt = 0; kt < 4; ++kt) {
            const short* kbase = Kp + (size_t)(kvb + kt * 16 + lo) * DH + hi * 8;
            kf0[kt] = *(const short8v*)(kbase);
            kf1[kt] = *(const short8v*)(kbase + 32);
        }
        // ---- V fragments, issued early: latency hides under softmax
        short8v vf0[4], vf1[4];
        #pragma unroll
        for (int dt = 0; dt < 4; ++dt) {
            const short* vbase = Vp + (size_t)(dt * 16 + lo) * S + kvb + hi * 8;
            vf0[dt] = *(const short8v*)(vbase);
            vf1[dt] = *(const short8v*)(vbase + 32);
        }

        // ---- QK^T, both tiles
        f32x4 sB[4], sF[4];
        #pragma unroll
        for (int kt = 0; kt < 4; ++kt) {
            f32x4 a = z;
            a = __builtin_amdgcn_mfma_f32_16x16x32_bf16(qB0, kf0[kt], a, 0, 0, 0);
            a = __builtin_amdgcn_mfma_f32_16x16x32_bf16(qB1, kf1[kt], a, 0, 0, 0);
            sB[kt] = a;
        }
        if (actF) {
            #pragma unroll
            for (int kt = 0; kt < 4; ++kt) {
                f32x4 a = z;
                a = __builtin_amdgcn_mfma_f32_16x16x32_bf16(qF0, kf0[kt], a, 0, 0, 0);
                a = __builtin_amdgcn_mfma_f32_16x16x32_bf16(qF1, kf1[kt], a, 0, 0, 0);
                sF[kt] = a;
            }
        }

        // ---- online softmax, two independent chains (ILP)
        #pragma unroll
        for (int rg = 0; rg < 4; ++rg) {
            {   // tile B
                const int q = q0B + hi * 4 + rg;
                float sv[4];
                float bm = -INFINITY;
                #pragma unroll
                for (int kt = 0; kt < 4; ++kt) {
                    float v = sB[kt][rg];
                    if (kvb + kt * 16 + lo > q) v = -INFINITY;
                    sv[kt] = v;
                    bm = fmaxf(bm, v);
                }
                bm = fmaxf(bm, __shfl_xor(bm, 1));
                bm = fmaxf(bm, __shfl_xor(bm, 2));
                bm = fmaxf(bm, __shfl_xor(bm, 4));
                bm = fmaxf(bm, __shfl_xor(bm, 8));
                const float mn = fmaxf(mB[rg], bm);
                float ps = 0.f;
                #pragma unroll
                for (int kt = 0; kt < 4; ++kt) {
                    const float pv = __expf(sv[kt] - mn);
                    ps += pv;
                    P[w][0][hi * 4 + rg][kt * 16 + lo] = __float2bfloat16(pv);
                }
                ps += __shfl_xor(ps, 1);
                ps += __shfl_xor(ps, 2);
                ps += __shfl_xor(ps, 4);
                ps += __shfl_xor(ps, 8);
                const float c = __expf(mB[rg] - mn);
                mB[rg] = mn;
                lB[rg] = lB[rg] * c + ps;
                #pragma unroll
                for (int dt = 0; dt < 4; ++dt) oB[dt][rg] *= c;
            }
            if (actF) {   // tile F
                const int q = q0F + hi * 4 + rg;
                float sv[4];
                float bm = -INFINITY;
                #pragma unroll
                for (int kt = 0; kt < 4; ++kt) {
                    float v = sF[kt][rg];
                    if (kvb + kt * 16 + lo > q) v = -INFINITY;
                    sv[kt] = v;
                    bm = fmaxf(bm, v);
                }
                bm = fmaxf(bm, __shfl_xor(bm, 1));
                bm = fmaxf(bm, __shfl_xor(bm, 2));
                bm = fmaxf(bm, __shfl_xor(bm, 4));
                bm = fmaxf(bm, __shfl_xor(bm, 8));
                const float mn = fmaxf(mF[rg], bm);
                float ps = 0.f;
                #pragma unroll
                for (int kt = 0; kt < 4; ++kt) {
                    const float pv = __expf(sv[kt] - mn);
                    ps += pv;
                    P[w][1][hi * 4 + rg][kt * 16 + lo] = __float2bfloat16(pv);
                }
                ps += __shfl_xor(ps, 1);
                ps += __shfl_xor(ps, 2);
                ps += __shfl_xor(ps, 4);
                ps += __shfl_xor(ps, 8);
                const float c = __expf(mF[rg] - mn);
                mF[rg] = mn;
                lF[rg] = lF[rg] * c + ps;
                #pragma unroll
                for (int dt = 0; dt < 4; ++dt) oF[dt][rg] *= c;
            }
        }

        asm volatile("s_waitcnt lgkmcnt(0)" ::: "memory");
        const short8v paB0 = *(const short8v*)&P[w][0][lo][hi * 8];
        const short8v paB1 = *(const short8v*)&P[w][0][lo][32 + hi * 8];
        const short8v paF0 = *(const short8v*)&P[w][1][lo][hi * 8];
        const short8v paF1 = *(const short8v*)&P[w][1][lo][32 + hi * 8];

        // ---- PV, both tiles, shared V fragments
        #pragma unroll
        for (int dt = 0; dt < 4; ++dt) {
            oB[dt] = __builtin_amdgcn_mfma_f32_16x16x32_bf16(paB0, vf0[dt], oB[dt], 0, 0, 0);
            oB[dt] = __builtin_amdgcn_mfma_f32_16x16x32_bf16(paB1, vf1[dt], oB[dt], 0, 0, 0);
            if (actF) {
                oF[dt] = __builtin_amdgcn_mfma_f32_16x16x32_bf16(paF0, vf0[dt], oF[dt], 0, 0, 0);
                oF[dt] = __builtin_amdgcn_mfma_f32_16x16x32_bf16(paF1, vf1[dt], oF[dt], 0, 0, 0);
            }
        }
    }

    // ---- epilogue, both tiles
    short* OpB = Oh + (size_t)(b * S + q0B) * DM + h * DH;
    short* OpF = Oh + (size_t)(b * S + q0F) * DM + h * DH;
    #pragma unroll
    for (int rg = 0; rg < 4; ++rg) {
        const float ivB = 1.0f / lB[rg];
        const float ivF = 1.0f / lF[rg];
        #pragma unroll
        for (int dt = 0; dt < 4; ++dt) {
            OpB[(size_t)(hi * 4 + rg) * DM + dt * 16 + lo] = f2bf(oB[dt][rg] * ivB);
            OpF[(size_t)(hi * 4 + rg) * DM + dt * 16 + lo] = f2bf(oF[dt][rg] * ivF);
        }
    }
}

// ---------------------------------------------------------------------------
extern "C" void kernel_launch(void* const* d_in, const int* in_sizes, int n_in,
                              void* d_out, int out_size, void* d_ws, size_t ws_size,
                              hipStream_t stream) {
    const float* x  = (const float*)d_in[0];
    const int*  pos = (const int*)d_in[1];
    const float* wq = (const float*)d_in[2];
    const float* wk = (const float*)d_in[3];
    const float* wv = (const float*)d_in[4];
    const float* wo = (const float*)d_in[5];
    float* out = (float*)d_out;

    const int S = in_sizes[1];              // 2048
    const int rows = in_sizes[0] / DM;      // B*S
    const int Bb = rows / S;

    short* xh   = (short*)d_ws;
    short* wqkv = xh + (size_t)rows * DM;
    short* woh  = wqkv + (size_t)QKV * DM;
    short* QKVr = woh + (size_t)DM * DM;
    short* Qh   = QKVr + (size_t)rows * QKV;
    short* Kh   = Qh + (size_t)rows * DM;
    short* Vt   = Kh + (size_t)rows * DM;
    short* Oh   = Vt + (size_t)rows * DM;

    const int nx = rows * DM;
    const int nw = DM * DM;
    const int ntot = nx + 4 * nw;
    convert_inputs<<<(ntot / 4 + 255) / 256, 256, 0, stream>>>(
        x, wq, wk, wv, wo, xh, wqkv, woh, nx, nw);

    gemm_bt_mfma<1><<<dim3(QKV / 128, rows / 128), 256, 0, stream>>>(
        xh, wqkv, QKVr, rows, QKV, DM);

    const int total = 2 * rows * (DM / 2);
    rope_bf16<<<(total + 255) / 256, 256, 0, stream>>>(QKVr, pos, Qh, Kh, S, rows);
    v_transpose_bf16<<<dim3(S / 64, Bb * NH), 256, 0, stream>>>(QKVr, Vt, S);

    attn_mfma<<<dim3(S / 128, NH, Bb), 256, 0, stream>>>(Qh, Kh, Vt, Oh, S);

    gemm_bt_mfma<0><<<dim3(DM / 128, rows / 128), 256, 0, stream>>>(
        Oh, woh, out, rows, DM, DM);
}

// Round 7
// 221.362 us; speedup vs baseline: 10.0510x; 1.0084x over previous
//
#include <hip/hip_runtime.h>
#include <hip/hip_bf16.h>
#include <math.h>

static constexpr int DM = 1024;   // d_model
static constexpr int NH = 16;     // heads
static constexpr int DH = 64;     // head dim
static constexpr int QKV = 3 * DM;

typedef __attribute__((ext_vector_type(8))) short short8v;  // 8 bf16 = 4 VGPR
typedef __attribute__((ext_vector_type(4))) float f32x4;

__device__ inline short f2bf(float x) {
    __hip_bfloat16 h = __float2bfloat16(x);
    return *reinterpret_cast<short*>(&h);
}

// async global->LDS, 16B per lane. LDS dst must be wave-uniform (HW writes
// lane i at dst + i*16); global src is per-lane.
__device__ inline void gload16(const void* g, void* l) {
    __builtin_amdgcn_global_load_lds(
        (const __attribute__((address_space(1))) unsigned int*)g,
        (__attribute__((address_space(3))) unsigned int*)l, 16, 0, 0);
}

// ---------------------------------------------------------------------------
// Fused fp32 -> bf16 convert for all five inputs (one launch).
// ---------------------------------------------------------------------------
__global__ __launch_bounds__(256)
void convert_inputs(const float* __restrict__ x,  const float* __restrict__ wq,
                    const float* __restrict__ wk, const float* __restrict__ wv,
                    const float* __restrict__ wo, short* __restrict__ xh,
                    short* __restrict__ wqkv, short* __restrict__ woh,
                    int nx, int nw) {
    const int i = (blockIdx.x * 256 + threadIdx.x) * 4;
    const float* src;
    short* dst;
    int off;
    if (i < nx)                { src = x;  dst = xh;            off = i; }
    else if (i < nx + nw)      { src = wq; dst = wqkv;          off = i - nx; }
    else if (i < nx + 2 * nw)  { src = wk; dst = wqkv + nw;     off = i - nx - nw; }
    else if (i < nx + 3 * nw)  { src = wv; dst = wqkv + 2 * nw; off = i - nx - 2 * nw; }
    else if (i < nx + 4 * nw)  { src = wo; dst = woh;           off = i - nx - 3 * nw; }
    else return;
    const float4 v = *(const float4*)(src + off);
    short4 o;
    o.x = f2bf(v.x); o.y = f2bf(v.y); o.z = f2bf(v.z); o.w = f2bf(v.w);
    *(short4*)(dst + off) = o;
}

// ---------------------------------------------------------------------------
// bf16 MFMA GEMM, m97 structure (unchanged, passing).
// ---------------------------------------------------------------------------
template <int BF16OUT>
__global__ __launch_bounds__(256)
void gemm_bt_mfma(const short* __restrict__ A, const short* __restrict__ B,
                  void* __restrict__ Cv, int M, int N, int K) {
    __shared__ __align__(16) short As[128 * 32];
    __shared__ __align__(16) short Bs[128 * 32];
    const int tid = threadIdx.x;
    const int w = tid >> 6, l = tid & 63;
    const int lo = l & 15, hi = l >> 4;
    const int wr = w >> 1, wc = w & 1;
    const size_t m0 = (size_t)blockIdx.y * 128;
    const size_t n0 = (size_t)blockIdx.x * 128;

    const int cr = (w * 2) * 16 + (l >> 2);
    const int cc = (l & 3) * 8;
    const short* Ag0 = A + (m0 + cr) * K + cc;
    const short* Ag1 = Ag0 + (size_t)16 * K;
    const short* Bg0 = B + (n0 + cr) * K + cc;
    const short* Bg1 = Bg0 + (size_t)16 * K;
    short* As0 = As + (w * 2) * 512;
    short* As1 = As0 + 512;
    short* Bs0 = Bs + (w * 2) * 512;
    short* Bs1 = Bs0 + 512;

    f32x4 acc[4][4];
    #pragma unroll
    for (int mi = 0; mi < 4; ++mi)
        #pragma unroll
        for (int nj = 0; nj < 4; ++nj)
            acc[mi][nj] = (f32x4){0.f, 0.f, 0.f, 0.f};

    const int aoff = (wr * 64 + lo) * 32 + hi * 8;
    const int boff = (wc * 64 + lo) * 32 + hi * 8;

    for (int k0 = 0; k0 < K; k0 += 32) {
        __syncthreads();
        gload16(Ag0 + k0, As0);
        gload16(Ag1 + k0, As1);
        gload16(Bg0 + k0, Bs0);
        gload16(Bg1 + k0, Bs1);
        __syncthreads();
        short8v af[4], bf[4];
        #pragma unroll
        for (int mi = 0; mi < 4; ++mi)
            af[mi] = *(const short8v*)&As[aoff + mi * 16 * 32];
        #pragma unroll
        for (int nj = 0; nj < 4; ++nj)
            bf[nj] = *(const short8v*)&Bs[boff + nj * 16 * 32];
        #pragma unroll
        for (int mi = 0; mi < 4; ++mi)
            #pragma unroll
            for (int nj = 0; nj < 4; ++nj)
                acc[mi][nj] = __builtin_amdgcn_mfma_f32_16x16x32_bf16(
                    af[mi], bf[nj], acc[mi][nj], 0, 0, 0);
    }

    const size_t mbase = m0 + wr * 64 + hi * 4;
    const size_t nbase = n0 + wc * 64 + lo;
    #pragma unroll
    for (int mi = 0; mi < 4; ++mi)
        #pragma unroll
        for (int nj = 0; nj < 4; ++nj)
            #pragma unroll
            for (int rg = 0; rg < 4; ++rg) {
                const size_t m = mbase + mi * 16 + rg;
                const size_t n = nbase + nj * 16;
                if (BF16OUT)
                    ((short*)Cv)[m * N + n] = f2bf(acc[mi][nj][rg]);
                else
                    ((float*)Cv)[m * N + n] = acc[mi][nj][rg];
            }
}

// ---------------------------------------------------------------------------
// RoPE on bf16 QKV buffer (Q scaled by 1/8). (unchanged, passing)
// ---------------------------------------------------------------------------
__global__ __launch_bounds__(256)
void rope_bf16(const short* __restrict__ QKVr, const int* __restrict__ pos,
               short* __restrict__ Qh, short* __restrict__ Kh, int S, int rows) {
    int idx = blockIdx.x * 256 + threadIdx.x;
    const int per = rows * (DM / 2);
    bool isK = false;
    if (idx >= per) { idx -= per; isK = true; }
    if (idx >= per) return;
    const int row = idx >> 9;
    const int rem = idx & 511;
    const int h = rem >> 5, k = rem & 31;
    const unsigned pin = *(const unsigned*)(QKVr + (size_t)row * QKV +
                                            (isK ? DM : 0) + h * DH + 2 * k);
    const float x0 = __uint_as_float(pin << 16);
    const float x1 = __uint_as_float(pin & 0xffff0000u);
    const float ang = (float)pos[row % S] * powf(10000.0f, -(float)k * (1.0f / 32.0f));
    const float c = cosf(ang), sn = sinf(ang);
    float y0 = c * x0 - sn * x1;
    float y1 = sn * x0 + c * x1;
    if (!isK) { y0 *= 0.125f; y1 *= 0.125f; }
    const int b = row / S, sr = row % S;
    short* dst = (isK ? Kh : Qh) + ((size_t)(b * NH + h) * S + sr) * DH + 2 * k;
    *(unsigned*)dst = ((unsigned)(unsigned short)f2bf(y1) << 16)
                    | (unsigned short)f2bf(y0);
}

// ---------------------------------------------------------------------------
// V slice of QKV buffer -> per-head transposed Vt[B*H][64][S]. (unchanged)
// ---------------------------------------------------------------------------
__global__ __launch_bounds__(256)
void v_transpose_bf16(const short* __restrict__ QKVr, short* __restrict__ Vt, int S) {
    __shared__ __align__(16) short T[64][72];
    const int bh = blockIdx.y;
    const int b = bh / NH, h = bh - b * NH;
    const int s0 = blockIdx.x * 64;
    const int tid = threadIdx.x;
    const int r = tid >> 2, seg = (tid & 3) * 16;
    const short* src = QKVr + (size_t)(b * S + s0 + r) * QKV + 2 * DM + h * DH + seg;
    const short8v a0 = *(const short8v*)(src);
    const short8v a1 = *(const short8v*)(src + 8);
    #pragma unroll
    for (int j = 0; j < 8; ++j) T[seg + j][r] = a0[j];
    #pragma unroll
    for (int j = 0; j < 8; ++j) T[seg + 8 + j][r] = a1[j];
    __syncthreads();
    const uint4* sv = (const uint4*)&T[r][seg];
    uint4* dv = (uint4*)&Vt[((size_t)bh * DH + r) * S + s0 + seg];
    dv[0] = sv[0]; dv[1] = sv[1];
}

// ---------------------------------------------------------------------------
// MFMA flash attention, R7 = R6 + softmax overhaul:
//  - row-sum via MFMA (l += P*ones; same (rg,lane) layout as o -> final
//    divide needs no cross-lane, and numerator/denominator share bf16 P);
//  - defer-max (T13, THR=8): local pmax + wave-uniform __any; shfl max
//    reduce + o/l rescale only when the running max actually grows;
//  - causal mask hoisted to each tile's LAST kv-block only (uniform branch).
// Dataflow/fragments otherwise identical to passing R6.
// ---------------------------------------------------------------------------
__global__ __launch_bounds__(256)
void attn_mfma(const short* __restrict__ Qh, const short* __restrict__ Kh,
               const short* __restrict__ Vt, short* __restrict__ Oh, int S) {
    __shared__ __align__(16) __hip_bfloat16 P[4][2][16][72];
    const int b = blockIdx.z, h = blockIdx.y;
    const int bh = b * NH + h;
    const int tid = threadIdx.x;
    const int w = tid >> 6, l = tid & 63;
    const int lo = l & 15, hi = l >> 4;
    const int T = S >> 4;
    const int p = blockIdx.x * 4 + w;
    const int q0B = (T - 1 - p) << 4;
    const int q0F = p << 4;
    const int nkbB = (q0B + 79) >> 6;
    const int nkbF = (q0F + 79) >> 6;

    const short* Qp = Qh + (size_t)bh * S * DH;
    const short* Kp = Kh + (size_t)bh * S * DH;
    const short* Vp = Vt + (size_t)bh * DH * S;

    const short8v qB0 = *(const short8v*)(Qp + (size_t)(q0B + lo) * DH + hi * 8);
    const short8v qB1 = *(const short8v*)(Qp + (size_t)(q0B + lo) * DH + 32 + hi * 8);
    const short8v qF0 = *(const short8v*)(Qp + (size_t)(q0F + lo) * DH + hi * 8);
    const short8v qF1 = *(const short8v*)(Qp + (size_t)(q0F + lo) * DH + 32 + hi * 8);

    short8v ones;
    #pragma unroll
    for (int i = 0; i < 8; ++i) ones[i] = (short)0x3F80;   // bf16 1.0

    f32x4 oB[4], oF[4];
    f32x4 laB = (f32x4){0.f, 0.f, 0.f, 0.f};
    f32x4 laF = (f32x4){0.f, 0.f, 0.f, 0.f};
    float mB[4], mF[4];
    #pragma unroll
    for (int i = 0; i < 4; ++i) {
        oB[i] = (f32x4){0.f, 0.f, 0.f, 0.f};
        oF[i] = (f32x4){0.f, 0.f, 0.f, 0.f};
        mB[i] = -INFINITY; mF[i] = -INFINITY;
    }
    const f32x4 z = (f32x4){0.f, 0.f, 0.f, 0.f};
    const float THR = 8.0f;

    // softmax for one tile: defer-max + P store; no sum reduce (done by MFMA)
    auto softmaxTile = [&](f32x4 (&s)[4], f32x4 (&o)[4], f32x4& la,
                           float (&m)[4], bool masked, int q0, int kvb, int tsel) {
        float sv[4][4], pmax[4];
        #pragma unroll
        for (int rg = 0; rg < 4; ++rg) {
            #pragma unroll
            for (int kt = 0; kt < 4; ++kt) {
                float v = s[kt][rg];
                if (masked && (kvb + kt * 16 + lo > q0 + hi * 4 + rg)) v = -INFINITY;
                sv[rg][kt] = v;
            }
            pmax[rg] = fmaxf(fmaxf(sv[rg][0], sv[rg][1]),
                             fmaxf(sv[rg][2], sv[rg][3]));
        }
        int need = 0;
        #pragma unroll
        for (int rg = 0; rg < 4; ++rg) need |= (pmax[rg] > m[rg] + THR);
        if (__any(need)) {
            #pragma unroll
            for (int rg = 0; rg < 4; ++rg) {
                float bm = pmax[rg];
                bm = fmaxf(bm, __shfl_xor(bm, 1));
                bm = fmaxf(bm, __shfl_xor(bm, 2));
                bm = fmaxf(bm, __shfl_xor(bm, 4));
                bm = fmaxf(bm, __shfl_xor(bm, 8));
                const float mn = fmaxf(m[rg], bm);
                const float c = __expf(m[rg] - mn);
                m[rg] = mn;
                la[rg] *= c;
                #pragma unroll
                for (int dt = 0; dt < 4; ++dt) o[dt][rg] *= c;
            }
        }
        #pragma unroll
        for (int rg = 0; rg < 4; ++rg)
            #pragma unroll
            for (int kt = 0; kt < 4; ++kt)
                P[w][tsel][hi * 4 + rg][kt * 16 + lo] =
                    __float2bfloat16(__expf(sv[rg][kt] - m[rg]));
    };

    for (int kb = 0; kb < nkbB; ++kb) {
        const int kvb = kb * 64;
        const bool actF = kb < nkbF;

        // ---- K fragments (shared by both tiles)
        short8v kf0[4], kf1[4];
        #pragma unroll
        for (int kt = 0; kt < 4; ++kt) {
            const short* kbase = Kp + (size_t)(kvb + kt * 16 + lo) * DH + hi * 8;
            kf0[kt] = *(const short8v*)(kbase);
            kf1[kt] = *(const short8v*)(kbase + 32);
        }
        // ---- V fragments, issued early: latency hides under softmax
        short8v vf0[4], vf1[4];
        #pragma unroll
        for (int dt = 0; dt < 4; ++dt) {
            const short* vbase = Vp + (size_t)(dt * 16 + lo) * S + kvb + hi * 8;
            vf0[dt] = *(const short8v*)(vbase);
            vf1[dt] = *(const short8v*)(vbase + 32);
        }

        // ---- QK^T, both tiles
        f32x4 sB[4], sF[4];
        #pragma unroll
        for (int kt = 0; kt < 4; ++kt) {
            f32x4 a = z;
            a = __builtin_amdgcn_mfma_f32_16x16x32_bf16(qB0, kf0[kt], a, 0, 0, 0);
            a = __builtin_amdgcn_mfma_f32_16x16x32_bf16(qB1, kf1[kt], a, 0, 0, 0);
            sB[kt] = a;
        }
        if (actF) {
            #pragma unroll
            for (int kt = 0; kt < 4; ++kt) {
                f32x4 a = z;
                a = __builtin_amdgcn_mfma_f32_16x16x32_bf16(qF0, kf0[kt], a, 0, 0, 0);
                a = __builtin_amdgcn_mfma_f32_16x16x32_bf16(qF1, kf1[kt], a, 0, 0, 0);
                sF[kt] = a;
            }
        }

        // ---- softmax (defer-max), mask only on each tile's last block
        softmaxTile(sB, oB, laB, mB, kb == nkbB - 1, q0B, kvb, 0);
        if (actF) softmaxTile(sF, oF, laF, mF, kb == nkbF - 1, q0F, kvb, 1);

        asm volatile("s_waitcnt lgkmcnt(0)" ::: "memory");
        const short8v paB0 = *(const short8v*)&P[w][0][lo][hi * 8];
        const short8v paB1 = *(const short8v*)&P[w][0][lo][32 + hi * 8];
        const short8v paF0 = *(const short8v*)&P[w][1][lo][hi * 8];
        const short8v paF1 = *(const short8v*)&P[w][1][lo][32 + hi * 8];

        // ---- row-sum via MFMA: la += P * ones (same layout as o)
        laB = __builtin_amdgcn_mfma_f32_16x16x32_bf16(paB0, ones, laB, 0, 0, 0);
        laB = __builtin_amdgcn_mfma_f32_16x16x32_bf16(paB1, ones, laB, 0, 0, 0);
        if (actF) {
            laF = __builtin_amdgcn_mfma_f32_16x16x32_bf16(paF0, ones, laF, 0, 0, 0);
            laF = __builtin_amdgcn_mfma_f32_16x16x32_bf16(paF1, ones, laF, 0, 0, 0);
        }

        // ---- PV, both tiles, shared V fragments
        #pragma unroll
        for (int dt = 0; dt < 4; ++dt) {
            oB[dt] = __builtin_amdgcn_mfma_f32_16x16x32_bf16(paB0, vf0[dt], oB[dt], 0, 0, 0);
            oB[dt] = __builtin_amdgcn_mfma_f32_16x16x32_bf16(paB1, vf1[dt], oB[dt], 0, 0, 0);
            if (actF) {
                oF[dt] = __builtin_amdgcn_mfma_f32_16x16x32_bf16(paF0, vf0[dt], oF[dt], 0, 0, 0);
                oF[dt] = __builtin_amdgcn_mfma_f32_16x16x32_bf16(paF1, vf1[dt], oF[dt], 0, 0, 0);
            }
        }
    }

    // ---- epilogue, both tiles (1/l from lacc, no cross-lane needed)
    short* OpB = Oh + (size_t)(b * S + q0B) * DM + h * DH;
    short* OpF = Oh + (size_t)(b * S + q0F) * DM + h * DH;
    #pragma unroll
    for (int rg = 0; rg < 4; ++rg) {
        const float ivB = 1.0f / laB[rg];
        const float ivF = 1.0f / laF[rg];
        #pragma unroll
        for (int dt = 0; dt < 4; ++dt) {
            OpB[(size_t)(hi * 4 + rg) * DM + dt * 16 + lo] = f2bf(oB[dt][rg] * ivB);
            OpF[(size_t)(hi * 4 + rg) * DM + dt * 16 + lo] = f2bf(oF[dt][rg] * ivF);
        }
    }
}

// ---------------------------------------------------------------------------
extern "C" void kernel_launch(void* const* d_in, const int* in_sizes, int n_in,
                              void* d_out, int out_size, void* d_ws, size_t ws_size,
                              hipStream_t stream) {
    const float* x  = (const float*)d_in[0];
    const int*  pos = (const int*)d_in[1];
    const float* wq = (const float*)d_in[2];
    const float* wk = (const float*)d_in[3];
    const float* wv = (const float*)d_in[4];
    const float* wo = (const float*)d_in[5];
    float* out = (float*)d_out;

    const int S = in_sizes[1];              // 2048
    const int rows = in_sizes[0] / DM;      // B*S
    const int Bb = rows / S;

    short* xh   = (short*)d_ws;
    short* wqkv = xh + (size_t)rows * DM;
    short* woh  = wqkv + (size_t)QKV * DM;
    short* QKVr = woh + (size_t)DM * DM;
    short* Qh   = QKVr + (size_t)rows * QKV;
    short* Kh   = Qh + (size_t)rows * DM;
    short* Vt   = Kh + (size_t)rows * DM;
    short* Oh   = Vt + (size_t)rows * DM;

    const int nx = rows * DM;
    const int nw = DM * DM;
    const int ntot = nx + 4 * nw;
    convert_inputs<<<(ntot / 4 + 255) / 256, 256, 0, stream>>>(
        x, wq, wk, wv, wo, xh, wqkv, woh, nx, nw);

    gemm_bt_mfma<1><<<dim3(QKV / 128, rows / 128), 256, 0, stream>>>(
        xh, wqkv, QKVr, rows, QKV, DM);

    const int total = 2 * rows * (DM / 2);
    rope_bf16<<<(total + 255) / 256, 256, 0, stream>>>(QKVr, pos, Qh, Kh, S, rows);
    v_transpose_bf16<<<dim3(S / 64, Bb * NH), 256, 0, stream>>>(QKVr, Vt, S);

    attn_mfma<<<dim3(S / 128, NH, Bb), 256, 0, stream>>>(Qh, Kh, Vt, Oh, S);

    gemm_bt_mfma<0><<<dim3(DM / 128, rows / 128), 256, 0, stream>>>(
        Oh, woh, out, rows, DM, DM);
}